// Round 8
// baseline (40785.388 us; speedup 1.0000x reference)
//
#include <hip/hip_runtime.h>
#include <hip/hip_bf16.h>
#include <stdint.h>

#define BS 512
#define D 1024
#define H 4096
#define T_STEPS 64
#define N_INNER 4
#define NBLK 512

typedef __attribute__((ext_vector_type(8))) _Float16 f16x8;
typedef __attribute__((ext_vector_type(4))) float f32x4;
typedef unsigned short u16;

__device__ __forceinline__ u16 f2h_bits(float f) {
    _Float16 h = (_Float16)f;
    return __builtin_bit_cast(u16, h);
}
__device__ __forceinline__ float h2f(u16 b) {
    return (float)__builtin_bit_cast(_Float16, b);
}
__device__ __forceinline__ float fast_tanh(float x) {
    float e = __expf(2.0f * x);
    return 1.0f - 2.0f / (e + 1.0f);
}

// system-scope (sc0 sc1) 2-byte store: bypasses XCD L1/L2, LLC-coherent.
__device__ __forceinline__ void st_short_sys(u16* p, unsigned v) {
    asm volatile("global_store_short %0, %1, off sc0 sc1"
                 :: "v"(p), "v"(v) : "memory");
}

// ---------------- prep kernels ----------------

// src [rows][cols] f32 -> dst_hi/dst_lo [cols][rows] fp16 (hi + residual lo)
__global__ __launch_bounds__(256) void transpose_split(
    const float* __restrict__ src, u16* __restrict__ dst_hi,
    u16* __restrict__ dst_lo, int rows, int cols) {
    __shared__ float tile[32][33];
    const int tx = threadIdx.x & 31;
    const int ty = threadIdx.x >> 5;
    const int c0 = blockIdx.x * 32, r0 = blockIdx.y * 32;
    #pragma unroll
    for (int i = ty; i < 32; i += 8)
        tile[i][tx] = src[(size_t)(r0 + i) * cols + c0 + tx];
    __syncthreads();
    #pragma unroll
    for (int i = ty; i < 32; i += 8) {
        const float v = tile[tx][i];
        const u16 hi = f2h_bits(v);
        const u16 lo = f2h_bits(v - h2f(hi));
        const size_t idx = (size_t)(c0 + i) * rows + r0 + tx;
        dst_hi[idx] = hi;
        dst_lo[idx] = lo;
    }
}

// also zeroes the barrier flag/gen arrays (u32 count = 512*32 + 8*32)
__global__ __launch_bounds__(256) void init_z(
    const float* __restrict__ z0, float* __restrict__ z_cur,
    u16* __restrict__ z_h, float* __restrict__ out, unsigned* bar) {
    const int i = blockIdx.x * 256 + threadIdx.x;
    const float v = z0[i];
    z_cur[i] = v;
    z_h[i] = f2h_bits(v);
    out[i] = v;
    if (i < NBLK * 32 + 8 * 32) bar[i] = 0u;
}

// ---------------- staging (rule #21: linear LDS dest, inverse-swizzled src) ----
// AUX: 0 = normal (L2-cached, weights); 17 = SC0|SC1 (LLC-coherent, hid/z).

// 64 rows x 64 cols fp16 (128 B rows)
template<int AUX>
__device__ __forceinline__ void stageA(
    const u16* __restrict__ src, u16* lds, int row0, int ldK, int k0, int tid) {
    #pragma unroll
    for (int i = 0; i < 2; ++i) {
        const int L = (i * 256 + tid) * 16;
        const int r = L >> 7;
        const int cb = (L & 127) ^ ((r & 7) << 4);
        const size_t goff = (size_t)(row0 + r) * ldK + k0 + (cb >> 1);
        const int ldsoff = (i * 256 + (tid & ~63)) * 8;
        __builtin_amdgcn_global_load_lds(
            (const __attribute__((address_space(1))) void*)(src + goff),
            (__attribute__((address_space(3))) void*)(lds + ldsoff), 16, 0, AUX);
    }
}

// 32 rows x 128 cols fp16 (256 B rows)
template<int AUX>
__device__ __forceinline__ void stageB(
    const u16* __restrict__ src, u16* lds, int row0, int ldK, int k0, int tid) {
    #pragma unroll
    for (int i = 0; i < 2; ++i) {
        const int L = (i * 256 + tid) * 16;
        const int r = L >> 8;
        const int cb = (L & 255) ^ ((r & 7) << 4);
        const size_t goff = (size_t)(row0 + r) * ldK + k0 + (cb >> 1);
        const int ldsoff = (i * 256 + (tid & ~63)) * 8;
        __builtin_amdgcn_global_load_lds(
            (const __attribute__((address_space(1))) void*)(src + goff),
            (__attribute__((address_space(3))) void*)(lds + ldsoff), 16, 0, AUX);
    }
}

// ---------------- flag-tree grid barrier (no atomic contention) ----------------
// flags: NBLK slots, 128-B strided. gen: 8 slots, 128-B strided.
// target is monotonically increasing -> no reset races.
// Arrival = one plain store to own line (parallel). Master polls all flags
// with 256 threads, then publishes gen to 8 striped lines; blocks spin on
// their stripe (~64 readers/line).
__device__ __forceinline__ void gbar(unsigned* flags, unsigned* gen,
                                     unsigned target) {
    asm volatile("s_waitcnt vmcnt(0)" ::: "memory");
    __syncthreads();
    const int bid = blockIdx.x;
    const int t = threadIdx.x;
    if (bid == 0) {
        #pragma unroll
        for (int b = 0; b < 2; ++b) {
            const int blk = t + b * 256;
            if (blk != 0) {
                while (__hip_atomic_load(&flags[blk * 32], __ATOMIC_ACQUIRE,
                                         __HIP_MEMORY_SCOPE_AGENT) < target)
                    __builtin_amdgcn_s_sleep(1);
            }
        }
        __syncthreads();
        if (t < 8)
            __hip_atomic_store(&gen[t * 32], target, __ATOMIC_RELEASE,
                               __HIP_MEMORY_SCOPE_AGENT);
    } else {
        if (t == 0) {
            __hip_atomic_store(&flags[bid * 32], target, __ATOMIC_RELEASE,
                               __HIP_MEMORY_SCOPE_AGENT);
            unsigned* g = &gen[(bid & 7) * 32];
            while (__hip_atomic_load(g, __ATOMIC_ACQUIRE,
                                     __HIP_MEMORY_SCOPE_AGENT) < target)
                __builtin_amdgcn_s_sleep(1);
        }
        __syncthreads();
    }
}

// ---------------- persistent ODE kernel ----------------
// 252 substeps; per substep:
//   phase A: hid = tanh(z @ W1 + b1)   [512x4096], 64x64 tiles, K=1024,
//            W1 split hi/lo (2 MFMA terms); hid stored sc0sc1
//   gbar
//   phase B: z += h*(hid @ W2 + b2)    [512x1024], 32x32 tiles, K=4096,
//            W2 split hi/lo, BK=128, wave-split-K(4) + LDS reduce,
//            fused Euler/traj epilogue; z_h stored sc0sc1
//   gbar
// Weights use plain loads -> stay resident in each XCD's L2 (never fenced).
__global__ __launch_bounds__(256, 2) void ode_all(
    const u16* __restrict__ W1T_hi, const u16* __restrict__ W1T_lo,
    const u16* __restrict__ W2T_hi, const u16* __restrict__ W2T_lo,
    const float* __restrict__ b1, const float* __restrict__ b2,
    const float* __restrict__ tptr,
    u16* __restrict__ hid, float* __restrict__ z_cur, u16* __restrict__ z_h,
    float* __restrict__ out, unsigned* flags, unsigned* gen) {
    __shared__ __align__(16) u16 lA[2][4096];
    __shared__ __align__(16) u16 lBh[2][4096];
    __shared__ __align__(16) u16 lBl[2][4096];

    const int tid = threadIdx.x;
    const int bid = blockIdx.x;
    const int wave = tid >> 6, lane = tid & 63;
    const int l15 = lane & 15, lgrp = lane >> 4;
    const int lk8 = lgrp * 8;
    const int wr = wave >> 1, wc = wave & 1;

    // XCD-grouped tile maps (bid&7 ~ XCD; per-XCD weight slice = 4 MB = L2)
    const int a_tn = (bid & 7) * 8 + ((bid >> 3) & 7);   // 0..63
    const int a_tm = bid >> 6;                            // 0..7
    const int a_m0 = a_tm * 64, a_n0 = a_tn * 64;
    const int b_tn = (bid & 7) * 4 + ((bid >> 3) & 3);   // 0..31
    const int b_tm = bid >> 5;                            // 0..15
    const int b_m0 = b_tm * 32, b_n0 = b_tn * 32;

    for (int step = 0; step < (T_STEPS - 1) * N_INNER; ++step) {
        const int iv = step >> 2, s = step & 3;

        // ================= phase A =================
        {
            f32x4 acc[2][2];
            #pragma unroll
            for (int mi = 0; mi < 2; ++mi)
                #pragma unroll
                for (int ni = 0; ni < 2; ++ni)
                    acc[mi][ni] = (f32x4){0.f, 0.f, 0.f, 0.f};

            stageA<17>(z_h,    lA[0],  a_m0, D, 0, tid);
            stageA<0>(W1T_hi, lBh[0], a_n0, D, 0, tid);
            stageA<0>(W1T_lo, lBl[0], a_n0, D, 0, tid);
            __syncthreads();
            int cur = 0;
            for (int kt = 0; kt < 16; ++kt) {
                if (kt < 15) {
                    stageA<17>(z_h,    lA[cur ^ 1],  a_m0, D, (kt + 1) * 64, tid);
                    stageA<0>(W1T_hi, lBh[cur ^ 1], a_n0, D, (kt + 1) * 64, tid);
                    stageA<0>(W1T_lo, lBl[cur ^ 1], a_n0, D, (kt + 1) * 64, tid);
                }
                const char* Ah = (const char*)lA[cur];
                const char* Bh = (const char*)lBh[cur];
                const char* Bl = (const char*)lBl[cur];
                #pragma unroll
                for (int kk = 0; kk < 64; kk += 32) {
                    f16x8 af[2], bfh[2], bfl[2];
                    #pragma unroll
                    for (int mi = 0; mi < 2; ++mi) {
                        const int row = wr * 32 + mi * 16 + l15;
                        const int cb = ((kk + lk8) * 2) ^ ((row & 7) << 4);
                        af[mi] = *(const f16x8*)(Ah + row * 128 + cb);
                    }
                    #pragma unroll
                    for (int ni = 0; ni < 2; ++ni) {
                        const int row = wc * 32 + ni * 16 + l15;
                        const int cb = ((kk + lk8) * 2) ^ ((row & 7) << 4);
                        bfh[ni] = *(const f16x8*)(Bh + row * 128 + cb);
                        bfl[ni] = *(const f16x8*)(Bl + row * 128 + cb);
                    }
                    #pragma unroll
                    for (int mi = 0; mi < 2; ++mi)
                        #pragma unroll
                        for (int ni = 0; ni < 2; ++ni) {
                            acc[mi][ni] = __builtin_amdgcn_mfma_f32_16x16x32_f16(
                                af[mi], bfh[ni], acc[mi][ni], 0, 0, 0);
                            acc[mi][ni] = __builtin_amdgcn_mfma_f32_16x16x32_f16(
                                af[mi], bfl[ni], acc[mi][ni], 0, 0, 0);
                        }
                }
                __syncthreads();
                cur ^= 1;
            }
            const int crow = a_m0 + wr * 32, ccol = a_n0 + wc * 32;
            #pragma unroll
            for (int mi = 0; mi < 2; ++mi)
                #pragma unroll
                for (int ni = 0; ni < 2; ++ni) {
                    const int col = ccol + ni * 16 + l15;
                    const float b = b1[col];
                    #pragma unroll
                    for (int r = 0; r < 4; ++r) {
                        const int row = crow + mi * 16 + lgrp * 4 + r;
                        const float v = fast_tanh(acc[mi][ni][r] + b);
                        st_short_sys(&hid[(size_t)row * H + col],
                                     (unsigned)f2h_bits(v));
                    }
                }
        }
        gbar(flags, gen, (unsigned)(step * 2 + 1));

        // ================= phase B =================
        {
            f32x4 acc[2][2];
            #pragma unroll
            for (int mi = 0; mi < 2; ++mi)
                #pragma unroll
                for (int ni = 0; ni < 2; ++ni)
                    acc[mi][ni] = (f32x4){0.f, 0.f, 0.f, 0.f};

            stageB<17>(hid,    lA[0],  b_m0, H, 0, tid);
            stageB<0>(W2T_hi, lBh[0], b_n0, H, 0, tid);
            stageB<0>(W2T_lo, lBl[0], b_n0, H, 0, tid);
            __syncthreads();
            int cur = 0;
            const int ck = wave * 32;   // this wave's K-quarter within BK=128
            for (int kt = 0; kt < 32; ++kt) {
                if (kt < 31) {
                    stageB<17>(hid,    lA[cur ^ 1],  b_m0, H, (kt + 1) * 128, tid);
                    stageB<0>(W2T_hi, lBh[cur ^ 1], b_n0, H, (kt + 1) * 128, tid);
                    stageB<0>(W2T_lo, lBl[cur ^ 1], b_n0, H, (kt + 1) * 128, tid);
                }
                const char* Ah = (const char*)lA[cur];
                const char* Bh = (const char*)lBh[cur];
                const char* Bl = (const char*)lBl[cur];
                f16x8 af[2], bfh[2], bfl[2];
                #pragma unroll
                for (int mi = 0; mi < 2; ++mi) {
                    const int row = mi * 16 + l15;
                    const int cb = ((ck + lk8) * 2) ^ ((row & 7) << 4);
                    af[mi] = *(const f16x8*)(Ah + row * 256 + cb);
                }
                #pragma unroll
                for (int ni = 0; ni < 2; ++ni) {
                    const int row = ni * 16 + l15;
                    const int cb = ((ck + lk8) * 2) ^ ((row & 7) << 4);
                    bfh[ni] = *(const f16x8*)(Bh + row * 256 + cb);
                    bfl[ni] = *(const f16x8*)(Bl + row * 256 + cb);
                }
                #pragma unroll
                for (int mi = 0; mi < 2; ++mi)
                    #pragma unroll
                    for (int ni = 0; ni < 2; ++ni) {
                        acc[mi][ni] = __builtin_amdgcn_mfma_f32_16x16x32_f16(
                            af[mi], bfh[ni], acc[mi][ni], 0, 0, 0);
                        acc[mi][ni] = __builtin_amdgcn_mfma_f32_16x16x32_f16(
                            af[mi], bfl[ni], acc[mi][ni], 0, 0, 0);
                    }
                __syncthreads();
                cur ^= 1;
            }
            // cross-wave K reduce via LDS (reuse lA: 4 waves x 4 KB)
            float* red = (float*)(&lA[0][0]);
            #pragma unroll
            for (int f = 0; f < 4; ++f)
                *(f32x4*)(red + wave * 1024 + f * 256 + lane * 4) =
                    acc[f >> 1][f & 1];
            __syncthreads();
            f32x4 sum = (f32x4){0.f, 0.f, 0.f, 0.f};
            #pragma unroll
            for (int src = 0; src < 4; ++src)
                sum += *(const f32x4*)(red + src * 1024 + wave * 256 + lane * 4);

            // fused Euler update epilogue: wave owns fragment (mi,ni)
            const int mi = wave >> 1, ni = wave & 1;
            const int col = b_n0 + ni * 16 + l15;
            const float bb = b2[col];
            const float hstep = fabsf(tptr[iv + 1] - tptr[iv]) * (1.0f / N_INNER);
            float* traj = (s == N_INNER - 1) ? out + (size_t)(iv + 1) * BS * D
                                             : nullptr;
            #pragma unroll
            for (int r = 0; r < 4; ++r) {
                const int row = b_m0 + mi * 16 + lgrp * 4 + r;
                const size_t idx = (size_t)row * D + col;
                const float v = z_cur[idx] + hstep * (sum[r] + bb);
                z_cur[idx] = v;                       // block-local: plain
                st_short_sys(&z_h[idx], (unsigned)f2h_bits(v));  // cross: sc1
                if (traj) traj[idx] = v;              // host-read: plain
            }
        }
        gbar(flags, gen, (unsigned)(step * 2 + 2));
    }
}

// ---------------- host ----------------

extern "C" void kernel_launch(void* const* d_in, const int* in_sizes, int n_in,
                              void* d_out, int out_size, void* d_ws, size_t ws_size,
                              hipStream_t stream) {
    const float* z0 = (const float*)d_in[0];
    const float* t  = (const float*)d_in[1];
    const float* W1 = (const float*)d_in[2];
    const float* b1 = (const float*)d_in[3];
    const float* W2 = (const float*)d_in[4];
    const float* b2 = (const float*)d_in[5];
    float* out = (float*)d_out;

    char* ws = (char*)d_ws;
    u16*      W1T_hi = (u16*)(ws);                      // [H][D] fp16, 8 MB
    u16*      W1T_lo = (u16*)(ws + (8u << 20));
    u16*      W2T_hi = (u16*)(ws + (16u << 20));        // [D][H] fp16, 8 MB
    u16*      W2T_lo = (u16*)(ws + (24u << 20));
    float*    z_cur  = (float*)(ws + (32u << 20));      // [BS][D] f32, 2 MB
    u16*      z_h    = (u16*)(ws + (34u << 20));        // [BS][D] fp16, 1 MB
    u16*      hid    = (u16*)(ws + (35u << 20));        // [BS][H] fp16, 4 MB
    unsigned* flags  = (unsigned*)(ws + (39u << 20));   // 512 x 128B
    unsigned* gen    = flags + NBLK * 32;               // 8 x 128B

    transpose_split<<<dim3(H / 32, D / 32), 256, 0, stream>>>(W1, W1T_hi, W1T_lo, D, H);
    transpose_split<<<dim3(D / 32, H / 32), 256, 0, stream>>>(W2, W2T_hi, W2T_lo, H, D);
    init_z<<<(BS * D) / 256, 256, 0, stream>>>(z0, z_cur, z_h, out, flags);

    ode_all<<<NBLK, 256, 0, stream>>>(
        W1T_hi, W1T_lo, W2T_hi, W2T_lo, b1, b2, t,
        hid, z_cur, z_h, out, flags, gen);
}

// Round 9
// 34721.490 us; speedup vs baseline: 1.1746x; 1.1746x over previous
//
#include <hip/hip_runtime.h>
#include <hip/hip_bf16.h>
#include <stdint.h>

#define BS 512
#define D 1024
#define H 4096
#define T_STEPS 64
#define N_INNER 4
#define NBLK 512

typedef __attribute__((ext_vector_type(8))) _Float16 f16x8;
typedef __attribute__((ext_vector_type(4))) float f32x4;
typedef unsigned short u16;

__device__ __forceinline__ u16 f2h_bits(float f) {
    _Float16 h = (_Float16)f;
    return __builtin_bit_cast(u16, h);
}
__device__ __forceinline__ float h2f(u16 b) {
    return (float)__builtin_bit_cast(_Float16, b);
}
__device__ __forceinline__ float fast_tanh(float x) {
    float e = __expf(2.0f * x);
    return 1.0f - 2.0f / (e + 1.0f);
}

// system-scope (sc0 sc1) 2-byte store: bypasses XCD L1/L2, LLC-coherent.
__device__ __forceinline__ void st_short_sys(u16* p, unsigned v) {
    asm volatile("global_store_short %0, %1, off sc0 sc1"
                 :: "v"(p), "v"(v) : "memory");
}

// ---------------- prep kernels ----------------

// src [rows][cols] f32 -> dst_hi/dst_lo [cols][rows] fp16 (hi + residual lo)
__global__ __launch_bounds__(256) void transpose_split(
    const float* __restrict__ src, u16* __restrict__ dst_hi,
    u16* __restrict__ dst_lo, int rows, int cols) {
    __shared__ float tile[32][33];
    const int tx = threadIdx.x & 31;
    const int ty = threadIdx.x >> 5;
    const int c0 = blockIdx.x * 32, r0 = blockIdx.y * 32;
    #pragma unroll
    for (int i = ty; i < 32; i += 8)
        tile[i][tx] = src[(size_t)(r0 + i) * cols + c0 + tx];
    __syncthreads();
    #pragma unroll
    for (int i = ty; i < 32; i += 8) {
        const float v = tile[tx][i];
        const u16 hi = f2h_bits(v);
        const u16 lo = f2h_bits(v - h2f(hi));
        const size_t idx = (size_t)(c0 + i) * rows + r0 + tx;
        dst_hi[idx] = hi;
        dst_lo[idx] = lo;
    }
}

__global__ __launch_bounds__(256) void init_z(
    const float* __restrict__ z0, float* __restrict__ z_cur,
    u16* __restrict__ z_h, float* __restrict__ out, unsigned* bar) {
    const int i = blockIdx.x * 256 + threadIdx.x;
    const float v = z0[i];
    z_cur[i] = v;
    z_h[i] = f2h_bits(v);
    out[i] = v;
    if (i == 0) { bar[0] = 0u; bar[1] = 0u; }
}

// ---------------- staging (rule #21: linear LDS dest, inverse-swizzled src) ----
// 512 threads -> one 16B global_load_lds per thread per 8 KB tile.
// AUX: 0 = normal (L2-cached, weights); 17 = SC0|SC1 (LLC-coherent, hid/z).

// 64 rows x 64 cols fp16 (128 B rows)
template<int AUX>
__device__ __forceinline__ void stageA(
    const u16* __restrict__ src, u16* lds, int row0, int ldK, int k0, int tid) {
    const int r = tid >> 3;
    const int cb = ((tid & 7) << 4) ^ ((r & 7) << 4);
    const size_t goff = (size_t)(row0 + r) * ldK + k0 + (cb >> 1);
    const int ldsoff = (tid & ~63) * 8;   // elems; wave-uniform base
    __builtin_amdgcn_global_load_lds(
        (const __attribute__((address_space(1))) void*)(src + goff),
        (__attribute__((address_space(3))) void*)(lds + ldsoff), 16, 0, AUX);
}

// 32 rows x 128 cols fp16 (256 B rows)
template<int AUX>
__device__ __forceinline__ void stageB(
    const u16* __restrict__ src, u16* lds, int row0, int ldK, int k0, int tid) {
    const int r = tid >> 4;
    const int cb = ((tid & 15) << 4) ^ ((r & 7) << 4);
    const size_t goff = (size_t)(row0 + r) * ldK + k0 + (cb >> 1);
    const int ldsoff = (tid & ~63) * 8;
    __builtin_amdgcn_global_load_lds(
        (const __attribute__((address_space(1))) void*)(src + goff),
        (__attribute__((address_space(3))) void*)(lds + ldsoff), 16, 0, AUX);
}

// ---------------- grid barrier (r7-proven: counting + relaxed spin) ----------
__device__ __forceinline__ void gbar(unsigned* bar) {
    asm volatile("s_waitcnt vmcnt(0)" ::: "memory");
    __syncthreads();
    if (threadIdx.x == 0) {
        const unsigned g =
            __hip_atomic_load(&bar[1], __ATOMIC_RELAXED, __HIP_MEMORY_SCOPE_AGENT);
        if (atomicAdd(&bar[0], 1u) == NBLK - 1u) {
            __hip_atomic_store(&bar[0], 0u, __ATOMIC_RELAXED, __HIP_MEMORY_SCOPE_AGENT);
            __hip_atomic_fetch_add(&bar[1], 1u, __ATOMIC_RELEASE, __HIP_MEMORY_SCOPE_AGENT);
        } else {
            while (__hip_atomic_load(&bar[1], __ATOMIC_RELAXED,
                                     __HIP_MEMORY_SCOPE_AGENT) == g)
                __builtin_amdgcn_s_sleep(2);
        }
    }
    __syncthreads();
}

// ---------------- persistent ODE kernel (8 waves/block, 16 waves/CU) --------
// 252 substeps; per substep:
//   phase A: hid = tanh(z @ W1 + b1)   [512x4096], 64x64 tiles, K=1024,
//            8 waves = 2 Mhalf x 4 Nquarter (32x16 each); W1 split hi/lo.
//   gbar
//   phase B: z += h*(hid @ W2 + b2)    [512x1024], 32x32 tiles, K=4096,
//            BK=128, 8 waves = 4 Ksplit x 2 Nhalf; LDS reduce; fused Euler.
//   gbar
// Weights: plain loads -> per-XCD L2-resident. Activations: sc1 (LLC-coherent).
__global__ __launch_bounds__(512, 4) void ode_all(
    const u16* __restrict__ W1T_hi, const u16* __restrict__ W1T_lo,
    const u16* __restrict__ W2T_hi, const u16* __restrict__ W2T_lo,
    const float* __restrict__ b1, const float* __restrict__ b2,
    const float* __restrict__ tptr,
    u16* __restrict__ hid, float* __restrict__ z_cur, u16* __restrict__ z_h,
    float* __restrict__ out, unsigned* bar) {
    __shared__ __align__(16) u16 lA[2][4096];
    __shared__ __align__(16) u16 lBh[2][4096];
    __shared__ __align__(16) u16 lBl[2][4096];

    const int tid = threadIdx.x;
    const int bid = blockIdx.x;
    const int wave = tid >> 6, lane = tid & 63;
    const int l15 = lane & 15, lgrp = lane >> 4;
    const int lk8 = lgrp * 8;

    // phase A wave roles: 2 M-halves x 4 N-quarters
    const int wrA = wave >> 2, wcA = wave & 3;
    // phase B wave roles: 4 K-quarters x 2 N-halves
    const int kqB = wave >> 1, nhB = wave & 1;
    const int ckB = kqB * 32;

    // XCD-grouped tile maps (bid&7 ~ XCD; per-XCD weight slice = 4 MB = L2)
    const int a_tn = (bid & 7) * 8 + ((bid >> 3) & 7);   // 0..63
    const int a_tm = bid >> 6;                            // 0..7
    const int a_m0 = a_tm * 64, a_n0 = a_tn * 64;
    const int b_tn = (bid & 7) * 4 + ((bid >> 3) & 3);   // 0..31
    const int b_tm = bid >> 5;                            // 0..15
    const int b_m0 = b_tm * 32, b_n0 = b_tn * 32;

    for (int step = 0; step < (T_STEPS - 1) * N_INNER; ++step) {
        const int iv = step >> 2, s = step & 3;

        // ================= phase A =================
        {
            f32x4 acc[2];
            acc[0] = (f32x4){0.f, 0.f, 0.f, 0.f};
            acc[1] = (f32x4){0.f, 0.f, 0.f, 0.f};

            stageA<17>(z_h,    lA[0],  a_m0, D, 0, tid);
            stageA<0>(W1T_hi, lBh[0], a_n0, D, 0, tid);
            stageA<0>(W1T_lo, lBl[0], a_n0, D, 0, tid);
            __syncthreads();
            int cur = 0;
            for (int kt = 0; kt < 16; ++kt) {
                if (kt < 15) {
                    stageA<17>(z_h,    lA[cur ^ 1],  a_m0, D, (kt + 1) * 64, tid);
                    stageA<0>(W1T_hi, lBh[cur ^ 1], a_n0, D, (kt + 1) * 64, tid);
                    stageA<0>(W1T_lo, lBl[cur ^ 1], a_n0, D, (kt + 1) * 64, tid);
                }
                const char* Ah = (const char*)lA[cur];
                const char* Bh = (const char*)lBh[cur];
                const char* Bl = (const char*)lBl[cur];
                #pragma unroll
                for (int kk = 0; kk < 64; kk += 32) {
                    f16x8 af[2], bh, bl;
                    #pragma unroll
                    for (int mi = 0; mi < 2; ++mi) {
                        const int row = wrA * 32 + mi * 16 + l15;
                        const int cb = ((kk + lk8) * 2) ^ ((row & 7) << 4);
                        af[mi] = *(const f16x8*)(Ah + row * 128 + cb);
                    }
                    {
                        const int row = wcA * 16 + l15;
                        const int cb = ((kk + lk8) * 2) ^ ((row & 7) << 4);
                        bh = *(const f16x8*)(Bh + row * 128 + cb);
                        bl = *(const f16x8*)(Bl + row * 128 + cb);
                    }
                    #pragma unroll
                    for (int mi = 0; mi < 2; ++mi) {
                        acc[mi] = __builtin_amdgcn_mfma_f32_16x16x32_f16(
                            af[mi], bh, acc[mi], 0, 0, 0);
                        acc[mi] = __builtin_amdgcn_mfma_f32_16x16x32_f16(
                            af[mi], bl, acc[mi], 0, 0, 0);
                    }
                }
                __syncthreads();
                cur ^= 1;
            }
            const int ccol = a_n0 + wcA * 16 + l15;
            const float b = b1[ccol];
            #pragma unroll
            for (int mi = 0; mi < 2; ++mi)
                #pragma unroll
                for (int r = 0; r < 4; ++r) {
                    const int row = a_m0 + wrA * 32 + mi * 16 + lgrp * 4 + r;
                    const float v = fast_tanh(acc[mi][r] + b);
                    st_short_sys(&hid[(size_t)row * H + ccol],
                                 (unsigned)f2h_bits(v));
                }
        }
        gbar(bar);

        // ================= phase B =================
        {
            f32x4 acc[2];
            acc[0] = (f32x4){0.f, 0.f, 0.f, 0.f};
            acc[1] = (f32x4){0.f, 0.f, 0.f, 0.f};

            stageB<17>(hid,    lA[0],  b_m0, H, 0, tid);
            stageB<0>(W2T_hi, lBh[0], b_n0, H, 0, tid);
            stageB<0>(W2T_lo, lBl[0], b_n0, H, 0, tid);
            __syncthreads();
            int cur = 0;
            for (int kt = 0; kt < 32; ++kt) {
                if (kt < 31) {
                    stageB<17>(hid,    lA[cur ^ 1],  b_m0, H, (kt + 1) * 128, tid);
                    stageB<0>(W2T_hi, lBh[cur ^ 1], b_n0, H, (kt + 1) * 128, tid);
                    stageB<0>(W2T_lo, lBl[cur ^ 1], b_n0, H, (kt + 1) * 128, tid);
                }
                const char* Ah = (const char*)lA[cur];
                const char* Bh = (const char*)lBh[cur];
                const char* Bl = (const char*)lBl[cur];
                f16x8 af[2], bh, bl;
                #pragma unroll
                for (int mi = 0; mi < 2; ++mi) {
                    const int row = mi * 16 + l15;
                    const int cb = ((ckB + lk8) * 2) ^ ((row & 7) << 4);
                    af[mi] = *(const f16x8*)(Ah + row * 256 + cb);
                }
                {
                    const int row = nhB * 16 + l15;
                    const int cb = ((ckB + lk8) * 2) ^ ((row & 7) << 4);
                    bh = *(const f16x8*)(Bh + row * 256 + cb);
                    bl = *(const f16x8*)(Bl + row * 256 + cb);
                }
                #pragma unroll
                for (int mi = 0; mi < 2; ++mi) {
                    acc[mi] = __builtin_amdgcn_mfma_f32_16x16x32_f16(
                        af[mi], bh, acc[mi], 0, 0, 0);
                    acc[mi] = __builtin_amdgcn_mfma_f32_16x16x32_f16(
                        af[mi], bl, acc[mi], 0, 0, 0);
                }
                __syncthreads();
                cur ^= 1;
            }
            // cross-wave K reduce via LDS (red = lA region, 16 KB)
            float* red = (float*)(&lA[0][0]);
            #pragma unroll
            for (int mi = 0; mi < 2; ++mi)
                *(f32x4*)(red + ((wave * 64 + lane) * 2 + mi) * 4) = acc[mi];
            __syncthreads();
            if (wave < 4) {
                const int nh2 = wave & 1, mi2 = wave >> 1;
                f32x4 sum = (f32x4){0.f, 0.f, 0.f, 0.f};
                #pragma unroll
                for (int kq = 0; kq < 4; ++kq)
                    sum += *(const f32x4*)(
                        red + (((kq * 2 + nh2) * 64 + lane) * 2 + mi2) * 4);

                const int col = b_n0 + nh2 * 16 + l15;
                const float bb = b2[col];
                const float hstep =
                    fabsf(tptr[iv + 1] - tptr[iv]) * (1.0f / N_INNER);
                float* traj = (s == N_INNER - 1)
                                  ? out + (size_t)(iv + 1) * BS * D : nullptr;
                #pragma unroll
                for (int r = 0; r < 4; ++r) {
                    const int row = b_m0 + mi2 * 16 + lgrp * 4 + r;
                    const size_t idx = (size_t)row * D + col;
                    const float v = z_cur[idx] + hstep * (sum[r] + bb);
                    z_cur[idx] = v;                      // block-local: plain
                    st_short_sys(&z_h[idx], (unsigned)f2h_bits(v));
                    if (traj) traj[idx] = v;             // host-read: plain
                }
            }
        }
        gbar(bar);
    }
}

// ---------------- host ----------------

extern "C" void kernel_launch(void* const* d_in, const int* in_sizes, int n_in,
                              void* d_out, int out_size, void* d_ws, size_t ws_size,
                              hipStream_t stream) {
    const float* z0 = (const float*)d_in[0];
    const float* t  = (const float*)d_in[1];
    const float* W1 = (const float*)d_in[2];
    const float* b1 = (const float*)d_in[3];
    const float* W2 = (const float*)d_in[4];
    const float* b2 = (const float*)d_in[5];
    float* out = (float*)d_out;

    char* ws = (char*)d_ws;
    u16*      W1T_hi = (u16*)(ws);                      // [H][D] fp16, 8 MB
    u16*      W1T_lo = (u16*)(ws + (8u << 20));
    u16*      W2T_hi = (u16*)(ws + (16u << 20));        // [D][H] fp16, 8 MB
    u16*      W2T_lo = (u16*)(ws + (24u << 20));
    float*    z_cur  = (float*)(ws + (32u << 20));      // [BS][D] f32, 2 MB
    u16*      z_h    = (u16*)(ws + (34u << 20));        // [BS][D] fp16, 1 MB
    u16*      hid    = (u16*)(ws + (35u << 20));        // [BS][H] fp16, 4 MB
    unsigned* bar    = (unsigned*)(ws + (39u << 20));   // [2]

    transpose_split<<<dim3(H / 32, D / 32), 256, 0, stream>>>(W1, W1T_hi, W1T_lo, D, H);
    transpose_split<<<dim3(D / 32, H / 32), 256, 0, stream>>>(W2, W2T_hi, W2T_lo, H, D);
    init_z<<<(BS * D) / 256, 256, 0, stream>>>(z0, z_cur, z_h, out, bar);

    ode_all<<<NBLK, 512, 0, stream>>>(
        W1T_hi, W1T_lo, W2T_hi, W2T_lo, b1, b2, t,
        hid, z_cur, z_h, out, bar);
}

// Round 10
// 8487.046 us; speedup vs baseline: 4.8056x; 4.0911x over previous
//
#include <hip/hip_runtime.h>
#include <hip/hip_bf16.h>
#include <stdint.h>

#define BS 512
#define D 1024
#define H 4096
#define T_STEPS 64
#define N_INNER 4
#define SK 4

typedef __attribute__((ext_vector_type(8))) _Float16 f16x8;
typedef __attribute__((ext_vector_type(4))) float f32x4;
typedef __attribute__((ext_vector_type(4))) unsigned short u16x4;
typedef unsigned short u16;

__device__ __forceinline__ u16 f2h_bits(float f) {
    _Float16 h = (_Float16)f;
    return __builtin_bit_cast(u16, h);
}
__device__ __forceinline__ float h2f(u16 b) {
    return (float)__builtin_bit_cast(_Float16, b);
}
__device__ __forceinline__ float fast_tanh(float x) {
    float e = __expf(2.0f * x);
    return 1.0f - 2.0f / (e + 1.0f);
}

// ---------------- prep kernels ----------------

// src [rows][cols] f32 -> dst_hi/dst_lo [cols][rows] fp16 (hi + residual lo)
__global__ __launch_bounds__(256) void transpose_split(
    const float* __restrict__ src, u16* __restrict__ dst_hi,
    u16* __restrict__ dst_lo, int rows, int cols) {
    __shared__ float tile[32][33];
    const int tx = threadIdx.x & 31;
    const int ty = threadIdx.x >> 5;
    const int c0 = blockIdx.x * 32, r0 = blockIdx.y * 32;
    #pragma unroll
    for (int i = ty; i < 32; i += 8)
        tile[i][tx] = src[(size_t)(r0 + i) * cols + c0 + tx];
    __syncthreads();
    #pragma unroll
    for (int i = ty; i < 32; i += 8) {
        const float v = tile[tx][i];
        const u16 hi = f2h_bits(v);
        const u16 lo = f2h_bits(v - h2f(hi));
        const size_t idx = (size_t)(c0 + i) * rows + r0 + tx;
        dst_hi[idx] = hi;
        dst_lo[idx] = lo;
    }
}

__global__ __launch_bounds__(256) void init_z(
    const float* __restrict__ z0, float* __restrict__ z_cur,
    u16* __restrict__ z_h, float* __restrict__ out) {
    const int i = blockIdx.x * 256 + threadIdx.x;
    const float v = z0[i];
    z_cur[i] = v;
    z_h[i] = f2h_bits(v);
    out[i] = v;
}

// ---------------- staging helper (rule #21 swizzle, r4-proven) ----------------
// 64x64 fp16 tile (128 B rows): linear LDS dest, inverse-swizzled global src.
// Each wave issues exactly 2 global_load_lds instructions here.
__device__ __forceinline__ void stage_one(
    const u16* __restrict__ src, u16* lds, int row0, int ldK, int k0, int tid) {
    #pragma unroll
    for (int i = 0; i < 2; ++i) {
        const int L = (i * 256 + tid) * 16;        // byte offset in tile
        const int r = L >> 7;
        const int cb = (L & 127) ^ ((r & 7) << 4);
        const size_t goff = (size_t)(row0 + r) * ldK + k0 + (cb >> 1);
        const int ldsoff = (i * 256 + (tid & ~63)) * 8;  // elems, wave-uniform
        __builtin_amdgcn_global_load_lds(
            (const __attribute__((address_space(1))) void*)(src + goff),
            (__attribute__((address_space(3))) void*)(lds + ldsoff), 16, 0, 0);
    }
}

// ---------------- fused fp16 GEMM: depth-3 pipeline, counted vmcnt -----------
// C = A[M][K] @ BT[N][K]^T ; A single fp16, B split hi/lo (2 MFMA terms).
// 64x64 tile, BK=64, 16 K-iterations, 4 waves (2x2) of 32x32.
// Pipeline: 3 LDS buffers; per iter: vmcnt(6) [stage kt landed; kt+1,kt+2
// in flight] -> raw s_barrier [also: all waves done reading buf (kt+2)%3]
// -> issue stage kt+2 -> compute kt. Never drains vmcnt to 0 in the loop.
// EPI==0: GEMM1 (K=1024, N=4096): hid = tanh(C+b1) fp16.
// EPI==1: GEMM2 split-K (K-slice=1024, N=1024): fp32 partials.
// XCD-grouped tile maps: per-XCD weight slice = 2 MB (fits 4 MB L2).
template<int EPI>
__global__ __launch_bounds__(256, 2) void gemm_step(
    const u16* __restrict__ A_h,
    const u16* __restrict__ B_hi, const u16* __restrict__ B_lo,
    const float* __restrict__ bias,
    u16* __restrict__ hid_out,
    float* __restrict__ part) {
    __shared__ __align__(16) u16 lA[3][4096];
    __shared__ __align__(16) u16 lBh[3][4096];
    __shared__ __align__(16) u16 lBl[3][4096];

    const int tid = threadIdx.x;
    const int bid = blockIdx.x;
    const int xcd = bid & 7, loc = bid >> 3;
    int tm, tn, sk, ldK;
    if (EPI == 0) {       // 8 tm x 64 tn; XCD owns 8 consecutive tn
        tn = xcd * 8 + (loc & 7);
        tm = loc >> 3;
        sk = 0;  ldK = D;
    } else {              // 4 sk x 8 tm x 16 tn; XCD owns 2 consecutive tn
        tn = xcd * 2 + (loc & 1);
        tm = (loc >> 1) & 7;
        sk = loc >> 4;  ldK = H;
    }
    const int m0 = tm * 64, n0 = tn * 64;
    const int k0b = sk * 1024;

    const int wave = tid >> 6;
    const int lane = tid & 63;
    const int wr = wave >> 1, wc = wave & 1;
    const int l15 = lane & 15;
    const int lgrp = lane >> 4;
    const int lk8 = lgrp * 8;

    f32x4 acc[2][2];
    #pragma unroll
    for (int mi = 0; mi < 2; ++mi)
        #pragma unroll
        for (int ni = 0; ni < 2; ++ni)
            acc[mi][ni] = (f32x4){0.f, 0.f, 0.f, 0.f};

    auto STAGE = [&](int buf, int kt) {
        const int k0 = k0b + kt * 64;
        stage_one(A_h,  lA[buf],  m0, ldK, k0, tid);
        stage_one(B_hi, lBh[buf], n0, ldK, k0, tid);
        stage_one(B_lo, lBl[buf], n0, ldK, k0, tid);   // 6 loads/wave total
    };
    auto COMPUTE = [&](int buf) {
        const char* Ah = (const char*)lA[buf];
        const char* Bh = (const char*)lBh[buf];
        const char* Bl = (const char*)lBl[buf];
        #pragma unroll
        for (int kk = 0; kk < 64; kk += 32) {
            f16x8 af[2], bfh[2], bfl[2];
            #pragma unroll
            for (int mi = 0; mi < 2; ++mi) {
                const int row = wr * 32 + mi * 16 + l15;
                const int cb = ((kk + lk8) * 2) ^ ((row & 7) << 4);
                af[mi] = *(const f16x8*)(Ah + row * 128 + cb);
            }
            #pragma unroll
            for (int ni = 0; ni < 2; ++ni) {
                const int row = wc * 32 + ni * 16 + l15;
                const int cb = ((kk + lk8) * 2) ^ ((row & 7) << 4);
                bfh[ni] = *(const f16x8*)(Bh + row * 128 + cb);
                bfl[ni] = *(const f16x8*)(Bl + row * 128 + cb);
            }
            #pragma unroll
            for (int mi = 0; mi < 2; ++mi)
                #pragma unroll
                for (int ni = 0; ni < 2; ++ni) {
                    acc[mi][ni] = __builtin_amdgcn_mfma_f32_16x16x32_f16(
                        af[mi], bfh[ni], acc[mi][ni], 0, 0, 0);
                    acc[mi][ni] = __builtin_amdgcn_mfma_f32_16x16x32_f16(
                        af[mi], bfl[ni], acc[mi][ni], 0, 0, 0);
                }
        }
    };

    // prologue: fill 2 of 3 buffers
    STAGE(0, 0);
    STAGE(1, 1);
    int cur = 0;
    for (int kt = 0; kt < 14; ++kt) {
        asm volatile("s_waitcnt vmcnt(6)" ::: "memory");  // stage kt landed
        asm volatile("s_barrier" ::: "memory");           // all waves: landed + buf free
        int nb = cur + 2; if (nb >= 3) nb -= 3;
        STAGE(nb, kt + 2);
        COMPUTE(cur);
        ++cur; if (cur == 3) cur = 0;
    }
    asm volatile("s_waitcnt vmcnt(6)" ::: "memory");      // stage 14 landed
    asm volatile("s_barrier" ::: "memory");
    COMPUTE(cur);
    ++cur; if (cur == 3) cur = 0;
    asm volatile("s_waitcnt vmcnt(0)" ::: "memory");      // stage 15 landed
    asm volatile("s_barrier" ::: "memory");
    COMPUTE(cur);

    // ---- epilogue (r4-identical) ----
    const int crow_base = m0 + wr * 32;
    const int ccol_base = n0 + wc * 32;
    if (EPI == 0) {
        #pragma unroll
        for (int mi = 0; mi < 2; ++mi)
            #pragma unroll
            for (int ni = 0; ni < 2; ++ni) {
                const int col = ccol_base + ni * 16 + l15;
                const float b = bias[col];
                #pragma unroll
                for (int r = 0; r < 4; ++r) {
                    const int row = crow_base + mi * 16 + lgrp * 4 + r;
                    const float v = fast_tanh(acc[mi][ni][r] + b);
                    hid_out[(size_t)row * H + col] = f2h_bits(v);
                }
            }
    } else {
        float* p = part + (size_t)sk * BS * D;
        #pragma unroll
        for (int mi = 0; mi < 2; ++mi)
            #pragma unroll
            for (int ni = 0; ni < 2; ++ni) {
                const int col = ccol_base + ni * 16 + l15;
                #pragma unroll
                for (int r = 0; r < 4; ++r) {
                    const int row = crow_base + mi * 16 + lgrp * 4 + r;
                    p[(size_t)row * D + col] = acc[mi][ni][r];
                }
            }
    }
}

// ---------------- split-K reduce + Euler update (r4-identical) ---------------
__global__ __launch_bounds__(256) void reduce_update(
    const float* __restrict__ part, const float* __restrict__ b2,
    const float* __restrict__ z_in, float* __restrict__ z_out,
    u16* __restrict__ zh,
    float* __restrict__ traj, const float* __restrict__ tptr, int iv) {
    const int i = (blockIdx.x * 256 + threadIdx.x) * 4;
    const size_t SZ = (size_t)BS * D;
    const float4 p0 = *(const float4*)(part + i);
    const float4 p1 = *(const float4*)(part + SZ + i);
    const float4 p2 = *(const float4*)(part + 2 * SZ + i);
    const float4 p3 = *(const float4*)(part + 3 * SZ + i);
    const float4 b  = *(const float4*)(b2 + (i & (D - 1)));
    const float4 z  = *(const float4*)(z_in + i);
    const float h = fabsf(tptr[iv + 1] - tptr[iv]) * (1.0f / N_INNER);
    float4 v;
    v.x = z.x + h * (p0.x + p1.x + p2.x + p3.x + b.x);
    v.y = z.y + h * (p0.y + p1.y + p2.y + p3.y + b.y);
    v.z = z.z + h * (p0.z + p1.z + p2.z + p3.z + b.z);
    v.w = z.w + h * (p0.w + p1.w + p2.w + p3.w + b.w);
    *(float4*)(z_out + i) = v;
    u16x4 h4;
    h4.x = f2h_bits(v.x);
    h4.y = f2h_bits(v.y);
    h4.z = f2h_bits(v.z);
    h4.w = f2h_bits(v.w);
    *(u16x4*)(zh + i) = h4;
    if (traj) *(float4*)(traj + i) = v;
}

// ---------------- host ----------------

extern "C" void kernel_launch(void* const* d_in, const int* in_sizes, int n_in,
                              void* d_out, int out_size, void* d_ws, size_t ws_size,
                              hipStream_t stream) {
    const float* z0 = (const float*)d_in[0];
    const float* t  = (const float*)d_in[1];
    const float* W1 = (const float*)d_in[2];
    const float* b1 = (const float*)d_in[3];
    const float* W2 = (const float*)d_in[4];
    const float* b2 = (const float*)d_in[5];
    float* out = (float*)d_out;

    char* ws = (char*)d_ws;
    u16*   W1T_hi = (u16*)(ws);                        // [H][D] fp16, 8 MB
    u16*   W1T_lo = (u16*)(ws + (8u << 20));
    u16*   W2T_hi = (u16*)(ws + (16u << 20));          // [D][H] fp16, 8 MB
    u16*   W2T_lo = (u16*)(ws + (24u << 20));
    float* z_cur  = (float*)(ws + (32u << 20));        // [BS][D] f32
    u16*   z_h    = (u16*)(ws + (34u << 20));          // [BS][D] fp16
    u16*   hid_h  = (u16*)(ws + (36u << 20));          // [BS][H] fp16
    float* part   = (float*)(ws + (44u << 20));        // SK x [BS][D] f32, 8 MB

    transpose_split<<<dim3(H / 32, D / 32), 256, 0, stream>>>(W1, W1T_hi, W1T_lo, D, H);
    transpose_split<<<dim3(D / 32, H / 32), 256, 0, stream>>>(W2, W2T_hi, W2T_lo, H, D);
    init_z<<<(BS * D) / 256, 256, 0, stream>>>(z0, z_cur, z_h, out);

    for (int iv = 0; iv < T_STEPS - 1; ++iv) {
        for (int s = 0; s < N_INNER; ++s) {
            gemm_step<0><<<512, 256, 0, stream>>>(
                z_h, W1T_hi, W1T_lo, b1, hid_h, nullptr);
            gemm_step<1><<<512, 256, 0, stream>>>(
                hid_h, W2T_hi, W2T_lo, nullptr, nullptr, part);
            float* traj = (s == N_INNER - 1) ? out + (size_t)(iv + 1) * BS * D : nullptr;
            reduce_update<<<512, 256, 0, stream>>>(
                part, b2, z_cur, z_cur, z_h, traj, t, iv);
        }
    }
}